// Round 15
// baseline (10934.737 us; speedup 1.0000x reference)
//
#include <hip/hip_runtime.h>
#include <hip/hip_bf16.h>
#include <stdint.h>

// Problem constants
#define T_LEN 2048
#define BATCH 32
#define HID   512
#define GDIM  2048            // 4*HID
#define NL    2
#define NBL   32              // blocks per layer
#define UPB   16              // hidden units per block
#define RSL   16              // ring slots
#define BH    (BATCH*HID)     // 16384
#define SLOTB (BH*2)          // 32768 B per ring slot (32 x 1KB block slices)
#define RINGB (RSL*SLOTB)     // 512 KB per ring

// flag zone (ints): flagsA64[64] (int64, stride 16 longs = 128B) | flagsB[64*32] | detect | abort | epoch
#define FZ_FB   2048
#define FZ_DET  4096
#define FZ_ABT  4160
#define FZ_EPO  4224          // int64 epoch slot (outside zeroed range)
#define FZ_TOT  4224          // zeroed range [0, FZ_TOT)
#define FZ_ALL  4240          // allocation

typedef __attribute__((ext_vector_type(8))) __bf16         bf16x8;
typedef __attribute__((ext_vector_type(8))) unsigned short u16x8;
typedef __attribute__((ext_vector_type(4))) unsigned short u16x4;
typedef __attribute__((ext_vector_type(4))) float          f32x4;

__device__ __forceinline__ unsigned short f2bf(float f) {
  unsigned int u = __builtin_bit_cast(unsigned int, f);
  u += 0x7FFFu + ((u >> 16) & 1u);
  return (unsigned short)(u >> 16);
}
__device__ __forceinline__ f32x4 pack8(f32x4 a, f32x4 b) {   // 8 f32 -> bf16x8 bits
  u16x8 r;
  r[0]=f2bf(a[0]); r[1]=f2bf(a[1]); r[2]=f2bf(a[2]); r[3]=f2bf(a[3]);
  r[4]=f2bf(b[0]); r[5]=f2bf(b[1]); r[6]=f2bf(b[2]); r[7]=f2bf(b[3]);
  return __builtin_bit_cast(f32x4, r);
}
__device__ __forceinline__ float sigm(float x)  { return 1.0f / (1.0f + __expf(-x)); }
__device__ __forceinline__ float tanh_(float x) { return 2.0f / (1.0f + __expf(-2.0f*x)) - 1.0f; }

// ---- scoped memory helpers (loads embed waitcnt unless caller drains) ----
__device__ __forceinline__ f32x4 ld16_pl(const void* p)  { f32x4 r; asm volatile("global_load_dwordx4 %0, %1, off"     : "=v"(r) : "v"(p)); return r; }
__device__ __forceinline__ f32x4 ld16_sc0(const void* p) { f32x4 r; asm volatile("global_load_dwordx4 %0, %1, off sc0" : "=v"(r) : "v"(p)); return r; }
__device__ __forceinline__ f32x4 ld16_sc1(const void* p) { f32x4 r; asm volatile("global_load_dwordx4 %0, %1, off sc1" : "=v"(r) : "v"(p)); return r; }
__device__ __forceinline__ int lddww_sc1(const void* p) {
  int r; asm volatile("global_load_dword %0, %1, off sc1\n\ts_waitcnt vmcnt(0)" : "=v"(r) : "v"(p) : "memory"); return r;
}
__device__ __forceinline__ long long ld64ww_sc1(const void* p) {
  long long r; asm volatile("global_load_dwordx2 %0, %1, off sc1\n\ts_waitcnt vmcnt(0)" : "=v"(r) : "v"(p) : "memory"); return r;
}
// NT load (round-15): non-temporal = no L1 allocation. Our polls never put the
// flag line into L1, so every poll is served by the XCD-local L2 — where the
// same-XCD producer's sc0 flag store lands. This is the "bypass L1, hit local
// L2" encoding that plain sc0 loads lack (r11: polled lines stick in L1).
__device__ __forceinline__ long long ld64ww_nt(const void* p) {
  long long r; asm volatile("global_load_dwordx2 %0, %1, off nt\n\ts_waitcnt vmcnt(0)" : "=v"(r) : "v"(p) : "memory"); return r;
}
__device__ __forceinline__ void st16_sc0(void* p, f32x4 v) { asm volatile("global_store_dwordx4 %0, %1, off sc0" :: "v"(p), "v"(v) : "memory"); }
__device__ __forceinline__ void st16_sc1(void* p, f32x4 v) { asm volatile("global_store_dwordx4 %0, %1, off sc1" :: "v"(p), "v"(v) : "memory"); }
__device__ __forceinline__ void st64_sc0(void* p, long long v) { asm volatile("global_store_dwordx2 %0, %1, off sc0" :: "v"(p), "v"(v) : "memory"); }
__device__ __forceinline__ void st64_sc1(void* p, long long v) { asm volatile("global_store_dwordx2 %0, %1, off sc1" :: "v"(p), "v"(v) : "memory"); }
__device__ __forceinline__ void stdw_sc1(void* p, int v) { asm volatile("global_store_dword %0, %1, off sc1" :: "v"(p), "v"(v) : "memory"); }
__device__ __forceinline__ void vm_drain() { asm volatile("s_waitcnt vmcnt(0)" ::: "memory"); }

// flagsA poll (round-15): epoch-exact values; fast mode polls via NT (L2)
// with an sc1 (L3) read every 8th spin as a safety net — the producer dual-
// stores the flag sc0 AND sc1, so whichever path is truthful observes it.
// Every failure mode degrades to the r9-proven sc1 behavior; never corrupts.
__device__ __forceinline__ void pollA(const long long* p, long long tgt, long long& seen,
                                      long long EPB, bool pl, bool fastm,
                                      int* abortp, bool& dead) {
  if (dead || __all(pl ? (seen >= tgt) : 1)) return;
  int spins = 0;
  for (;;) {
    long long v;
    if (fastm && ((spins & 7) != 7)) v = ld64ww_nt(p);
    else                             v = ld64ww_sc1(p);
    if (pl && (v & ~0xFFFLL) == EPB && v > seen) seen = v;
    if (__all(pl ? (seen >= tgt) : 1)) break;
    if (((++spins) & 255) == 0) {
      if (lddww_sc1(abortp)) { dead = true; break; }
      if (spins >= (1 << 21)) { stdw_sc1(abortp, 1); dead = true; break; }
    }
  }
}

// ---------------- prep kernels ----------------

__global__ void prep_misc(const float* __restrict__ b_ih, const float* __restrict__ b_hh,
                          const float* __restrict__ h0,
                          int* __restrict__ flagz, float* __restrict__ bsum,
                          char* __restrict__ ring0, char* __restrict__ ring1s) {
  int i = blockIdx.x * blockDim.x + threadIdx.x;   // 33024 threads
  if (i < FZ_TOT) flagz[i] = 0;
  if (i == FZ_TOT) {   // launch epoch from the free-running RTC: monotonic
    // across launches/replays. flagsA readers accept ONLY exact-epoch values,
    // so stale or garbage cache lines can never satisfy a poll.
    unsigned long long rt = __builtin_amdgcn_s_memrealtime();
    *(long long*)(flagz + FZ_EPO) = (long long)(rt >> 13);
  }
  if (i < NL*GDIM) bsum[i] = b_ih[i] + b_hh[i];
  if (i < NL*BH) {                                  // ring slot-0, per-block 1KB slices
    int layer = i >> 14, e = i & 16383;
    int b = e >> 9, u = e & 511;
    unsigned short v = f2bf(h0[((size_t)layer*BATCH + b)*HID + u]);
    size_t off = (size_t)(u >> 4)*1024 + (size_t)b*32 + (size_t)(u & 15)*2;
    *(unsigned short*)(ring0  + (size_t)layer*RINGB + off) = v;
    *(unsigned short*)(ring1s + (size_t)layer*RINGB + off) = v;
  }
}

__global__ void prep_w(const float* __restrict__ wih, const float* __restrict__ whh,
                       unsigned short* __restrict__ wihb, unsigned short* __restrict__ whhb) {
  const int n4 = NL*GDIM*HID/4;
  for (int i = blockIdx.x*blockDim.x + threadIdx.x; i < 2*n4; i += gridDim.x*blockDim.x) {
    const float*    src = (i < n4) ? wih  : whh;
    unsigned short* dst = (i < n4) ? wihb : whhb;
    int j = (i < n4) ? i : i - n4;
    f32x4 v = *((const f32x4*)src + j);
    u16x4 o; o[0]=f2bf(v[0]); o[1]=f2bf(v[1]); o[2]=f2bf(v[2]); o[3]=f2bf(v[3]);
    *((u16x4*)dst + j) = o;
  }
}

// ---------------- persistent LSTM ----------------
// ROUND-15 = r14 structure (r9-proven protocol + publisher/poller wave split)
// + ONE mechanism change: intra-layer flagsA go through the XCD-LOCAL L2.
//   producer (fast): ring data sc0 -> drain -> flagA sc0 store AND sc1 mirror.
//   consumer (fast): NT polls (no L1 allocation -> always served by local L2)
//   with periodic sc1 reads as the safety net. Values epoch-exact.
// flagsB/detect/abort remain sc1 (proven). Slow mode = all sc1 (r9 exact).

__global__ __launch_bounds__(512, 2) void lstm_persist(
    const float* __restrict__ x, const float* __restrict__ c0,
    const unsigned short* __restrict__ wihb, const unsigned short* __restrict__ whhb,
    const float* __restrict__ bsum,
    char* __restrict__ ring0, char* __restrict__ ring1s,
    int* __restrict__ flagz, float* __restrict__ out) {

  const int bid = blockIdx.x;
  const int r8  = bid & 7;
  if (r8 >= NL) return;
  const int layer = r8;
  const int lb    = bid >> 3;                 // 0..31
  const int actIdx = layer*NBL + lb;          // 0..63
  const int tid  = threadIdx.x;
  const int lane = tid & 63;
  const int wave = tid >> 6;                  // 0..7
  const int mh = wave & 1, nh = wave >> 1;    // batch-half, row-group (0..3)
  const int col = lane & 15, kg = lane >> 4;
  const int gt  = col & 3;                    // gate index (i,f,g,o)
  const int uu  = nh*4 + (col >> 2);          // unit-local 0..15
  const int u0  = lb * UPB;
  const int gu  = u0 + uu;                    // global hidden unit
  const int grow = gt*HID + gu;               // gate-matrix row
  const int tb  = mh*16 + kg*4 + gt;          // this thread's batch (post-transpose)

  long long* flagsA64 = (long long*)flagz;    // 64 flags, stride 16 longs (128B)
  int* flagsB = flagz + FZ_FB;
  int* detect = flagz + FZ_DET;
  int* abortp = flagz + FZ_ABT;

  __shared__ __align__(16) f32x4 smem[4096];           // h frags [0,2048), x frags [2048,4096)
  __shared__ __align__(16) unsigned short hbuf16[512]; // h slice [batch][unit] bf16, 1KB
  __shared__ __align__(16) float houtf[512];           // h slice f32 (layer-1 out), 2KB

  // ---- weight fragments (register-file resident; in-loop touches pin) ----
  f32x4 wfx[16], wfh[16];
  {
    const unsigned short* wxr = wihb + ((size_t)(layer*GDIM + grow))*HID + kg*8;
    const unsigned short* whr = whhb + ((size_t)(layer*GDIM + grow))*HID + kg*8;
#pragma unroll
    for (int ks = 0; ks < 16; ++ks) {
      wfx[ks] = *(const f32x4*)(wxr + ks*32);
      wfh[ks] = *(const f32x4*)(whr + ks*32);
    }
  }

  // ---- per-thread cell state ----
  float c = c0[((size_t)layer*BATCH + tb)*HID + gu];
  const float bi  = bsum[layer*GDIM + 0*HID + gu];
  const float bfv = bsum[layer*GDIM + 1*HID + gu];
  const float bg  = bsum[layer*GDIM + 2*HID + gu];
  const float bo  = bsum[layer*GDIM + 3*HID + gu];

  char* ringF = ring0  + (size_t)layer*RINGB;   // sc0 own-layer ring (fast data)
  char* ringS = ring1s + (size_t)layer*RINGB;   // sc1 own-layer ring
  const char* ringPrev = ring1s;                 // layer-0's sc1 ring (x for layer 1)
  long long* myfA64 = flagsA64 + actIdx*16;
  int* myfB = flagsB + actIdx*32;
  const bool pl = lane < NBL;
  const long long* fpOwnA64 = flagsA64 + (layer*NBL + (lane & 31))*16;
  const int* fpOthB = flagsB + ((1-layer)*NBL + (lane & 31))*32;
  int seenOth = 0;
  bool dead = false;

  // ---- launch epoch (published by prep; L3-direct read) ----
  const long long EPB = ld64ww_sc1(flagz + FZ_EPO) << 12;
  long long seenOwn = EPB;          // t=0 target (EPB|0) trivially satisfied

  // ---- placement detection (sc1-only) ----
  int xcc = 0;
  asm volatile("s_getreg_b32 %0, hwreg(HW_REG_XCC_ID)" : "=s"(xcc));
  if (tid == 0) stdw_sc1(detect + actIdx, xcc + 1);
  int dv = 0;
  {
    int spins = 0;
    for (;;) {
      if (dv == 0) dv = lddww_sc1(detect + lane);
      if (__all(dv != 0)) break;
      if (((++spins) & 255) == 0) {
        if (lddww_sc1(abortp)) { dead = true; break; }
        if (spins >= (1 << 20)) { stdw_sc1(abortp, 1); dead = true; break; }
      }
    }
  }
  const int dref0 = __shfl(dv, 0, 64), dref1 = __shfl(dv, 32, 64);
  const bool fastL0 = __all((lane < 32) ? (dv != 0 && dv == dref0) : 1);
  const bool fastL1 = __all((lane >= 32) ? (dv != 0 && dv == dref1) : 1);
  const bool fast = (layer ? fastL1 : fastL0) && !dead;

  // reader address pieces (fragment id -> slice byte offset within a slot)
  int roff[4];
#pragma unroll
  for (int q = 0; q < 4; ++q) {
    int id = q*512 + tid;
    int mh2 = id >> 10, ks2 = (id >> 6) & 15, lf = id & 63;
    int ug = ks2*32 + (lf >> 4)*8;
    int batch = mh2*16 + (lf & 15);
    roff[q] = (ug >> 4)*1024 + batch*32 + (ug & 8)*2;
  }

  const int pubw = (layer == 0) ? 2 : 4;   // publisher wave for the primary ring

  for (int t = 0; t < T_LEN; ++t) {
    const int slotR = t & (RSL-1);
    const int slotW = (t+1) & (RSL-1);

    // ---- 0. pin weights (loop-carried opaque touch) ----
#pragma unroll
    for (int ks = 0; ks < 16; ++ks)
      asm volatile("" : "+v"(wfx[ks]), "+v"(wfh[ks]));

    // ---- 1. layer-0 x prefetch ONLY (immutable global x, no flag dependency) ----
    f32x4 xpre[8];
    if (layer == 0) {
#pragma unroll
      for (int q = 0; q < 4; ++q) {
        int id = q*512 + tid;
        int mh2 = id >> 10, ks2 = (id >> 6) & 15, lf = id & 63;
        const float* s = x + ((size_t)t*BATCH + mh2*16 + (lf & 15))*HID + ks2*32 + (lf >> 4)*8;
        xpre[2*q]   = ld16_pl(s);
        xpre[2*q+1] = ld16_pl(s + 4);
      }
    }

    // ---- 2. polls: wave0 = flagsA (NT/L2 fast path); wave1 = flagsB (sc1) ----
    if (wave == 0)
      pollA(fpOwnA64, EPB | (long long)t, seenOwn, EPB, pl, fast, abortp, dead);
    if (wave == 1 && !dead) {
      const int tgt = (layer == 0) ? (t - 14) : (t + 1);
      int spins = 0;
      while (!__all(pl ? (seenOth >= tgt) : 1)) {
        if (pl && seenOth < tgt) { int v = lddww_sc1(fpOthB); if (v > seenOth) seenOth = v; }
        if (((++spins) & 255) == 0) {
          if (lddww_sc1(abortp)) { dead = true; break; }
          if (spins >= (1 << 21)) { stdw_sc1(abortp, 1); dead = true; break; }
        }
      }
    }
    __syncthreads();   // B0: all deps confirmed for the whole block

    // ---- 3. dependent loads (AFTER B0): xq then hq ----
    f32x4 xq[4], hq[4];
    if (layer == 1) {
      const char* p = ringPrev + (size_t)slotW*SLOTB;
#pragma unroll
      for (int q = 0; q < 4; ++q) xq[q] = ld16_sc1(p + roff[q]);
    }
    if (fast && t > 0) {
      const char* p = ringF + (size_t)slotR*SLOTB;
#pragma unroll
      for (int q = 0; q < 4; ++q) hq[q] = ld16_sc0(p + roff[q]);
    } else {
      const char* p = ringS + (size_t)slotR*SLOTB;
#pragma unroll
      for (int q = 0; q < 4; ++q) hq[q] = ld16_sc1(p + roff[q]);
    }
    vm_drain();   // all asm loads (xpre/xq/hq) now valid

    // ---- 4. stage to LDS (fragment permutation happens here) ----
#pragma unroll
    for (int q = 0; q < 4; ++q) smem[q*512 + tid] = hq[q];
    if (layer == 0) {
#pragma unroll
      for (int q = 0; q < 4; ++q) smem[2048 + q*512 + tid] = pack8(xpre[2*q], xpre[2*q+1]);
    } else {
#pragma unroll
      for (int q = 0; q < 4; ++q) smem[2048 + q*512 + tid] = xq[q];
    }
    __syncthreads();   // B1

    // layer-1 progress flag (ringPrev reads for step t complete) — early
    if (layer == 1 && wave == 1 && lane == 0) stdw_sc1(myfB, t + 1);

    // ---- 5. fragment reads + two independent MFMA chains ----
    f32x4 accx = {0.f,0.f,0.f,0.f}, acch = {0.f,0.f,0.f,0.f};
    {
      const f32x4* hb = (const f32x4*)smem;
      const f32x4* xb = (const f32x4*)smem + 2048;
#pragma unroll
      for (int ks = 0; ks < 16; ++ks) {
        f32x4 ah = hb[(mh*16 + ks)*64 + lane];
        f32x4 av = xb[(mh*16 + ks)*64 + lane];
        accx = __builtin_amdgcn_mfma_f32_16x16x32_bf16(
                 __builtin_bit_cast(bf16x8, av), __builtin_bit_cast(bf16x8, wfx[ks]), accx, 0,0,0);
        acch = __builtin_amdgcn_mfma_f32_16x16x32_bf16(
                 __builtin_bit_cast(bf16x8, ah), __builtin_bit_cast(bf16x8, wfh[ks]), acch, 0,0,0);
      }
    }
    const f32x4 acc = accx + acch;

    // ---- 6. in-wave 4x4 butterfly transpose -> (1 batch x 4 gates) ----
    float m0 = acc[0], m1 = acc[1], m2 = acc[2], m3 = acc[3];
    {
      float s0 = __shfl_xor(m0, 1), s1 = __shfl_xor(m1, 1),
            s2 = __shfl_xor(m2, 1), s3 = __shfl_xor(m3, 1);
      if (gt & 1) { m0 = s1; m2 = s3; } else { m1 = s0; m3 = s2; }
      s0 = __shfl_xor(m0, 2); s1 = __shfl_xor(m1, 2);
      s2 = __shfl_xor(m2, 2); s3 = __shfl_xor(m3, 2);
      if (gt & 2) { m0 = s2; m1 = s3; } else { m2 = s0; m3 = s1; }
    }
    const float iv = sigm(m0 + bi), fv = sigm(m1 + bfv);
    const float gv = tanh_(m2 + bg), ov = sigm(m3 + bo);
    c = fv*c + iv*gv;
    const float h = ov * tanh_(c);

    // ---- 7. gather h into LDS ----
    hbuf16[tb*16 + uu] = f2bf(h);
    if (layer == 1) houtf[tb*16 + uu] = h;
    if (t == T_LEN-1) {
      out[(size_t)T_LEN*BH + ((size_t)layer*BATCH + tb)*HID + gu] = h;
      out[(size_t)T_LEN*BH + (size_t)NL*BH + ((size_t)layer*BATCH + tb)*HID + gu] = c;
    }
    __syncthreads();   // B4: hbuf16/houtf complete

    // ---- 8. publish (dedicated waves; pollers fall through to next polls) ----
    if (wave == pubw) {
      f32x4 v = *(const f32x4*)((const char*)hbuf16 + lane*16);
      char* d = (fast ? ringF : ringS) + (size_t)slotW*SLOTB + lb*1024 + lane*16;
      if (fast) st16_sc0(d, v); else st16_sc1(d, v);
      vm_drain();
      if (lane == 0) {
        long long fv2 = EPB | (long long)(t + 1);
        if (fast) { st64_sc0(myfA64, fv2); st64_sc1(myfA64, fv2); }
        else      { st64_sc1(myfA64, fv2); }
        if (layer == 0 && !fast) stdw_sc1(myfB, t + 1);
      }
    } else if (wave == 3 && layer == 0 && fast) {
      f32x4 v = *(const f32x4*)((const char*)hbuf16 + lane*16);
      st16_sc1(ringS + (size_t)slotW*SLOTB + lb*1024 + lane*16, v);
      vm_drain();
      if (lane == 0) stdw_sc1(myfB, t + 1);
    } else if (layer == 1 && (wave == 2 || wave == 3)) {
      int l2 = (wave - 2)*64 + lane;          // 0..127 -> 16B chunks of 2KB
      int b2 = l2 >> 2, part = l2 & 3;
      f32x4 v = *(const f32x4*)((const char*)houtf + b2*64 + part*16);
      *(f32x4*)(out + (size_t)t*BH + (size_t)b2*HID + u0 + part*4) = v;
    }
  }

  // ---- terminal publish: drain everything, advertise completion ----
  vm_drain();
  __syncthreads();
  if (tid == 0) {
    long long fv2 = EPB | (long long)(T_LEN + 1);
    if (fast) { st64_sc0(myfA64, fv2); st64_sc1(myfA64, fv2); }
    else      { st64_sc1(myfA64, fv2); }
    stdw_sc1(myfB, T_LEN + 1);
  }
}

// ---------------- host launch ----------------

extern "C" void kernel_launch(void* const* d_in, const int* in_sizes, int n_in,
                              void* d_out, int out_size, void* d_ws, size_t ws_size,
                              hipStream_t stream) {
  const float* x    = (const float*)d_in[0];
  const float* w_ih = (const float*)d_in[1];
  const float* w_hh = (const float*)d_in[2];
  const float* b_ih = (const float*)d_in[3];
  const float* b_hh = (const float*)d_in[4];
  const float* h0   = (const float*)d_in[5];
  const float* c0   = (const float*)d_in[6];
  float* out = (float*)d_out;

  char* ws = (char*)d_ws;
  size_t off = 0;
  auto alloc = [&](size_t bytes) -> void* {
    off = (off + 255) & ~(size_t)255;
    void* p = ws + off;
    off += bytes;
    return p;
  };
  int*            flagz = (int*)alloc((size_t)FZ_ALL * sizeof(int));
  float*          bsum  = (float*)alloc((size_t)NL*GDIM*sizeof(float));
  char*           ring0 = (char*)alloc((size_t)NL*RINGB);
  char*           ring1s= (char*)alloc((size_t)NL*RINGB);
  unsigned short* wihb  = (unsigned short*)alloc((size_t)NL*GDIM*HID*2);
  unsigned short* whhb  = (unsigned short*)alloc((size_t)NL*GDIM*HID*2);
  (void)ws_size;

  prep_misc<<<129, 256, 0, stream>>>(b_ih, b_hh, h0, flagz, bsum, ring0, ring1s);
  prep_w<<<1024, 256, 0, stream>>>(w_ih, w_hh, wihb, whhb);
  lstm_persist<<<256, 512, 0, stream>>>(x, c0, wihb, whhb, bsum,
                                        ring0, ring1s, flagz, out);
  (void)in_sizes; (void)n_in; (void)out_size;
}

// Round 17
// 8738.353 us; speedup vs baseline: 1.2513x; 1.2513x over previous
//
#include <hip/hip_runtime.h>
#include <hip/hip_bf16.h>
#include <stdint.h>

// Problem constants
#define T_LEN 2048
#define BATCH 32
#define HID   512
#define GDIM  2048            // 4*HID
#define NL    2
#define NBL   32              // blocks per layer
#define UPB   16              // hidden units per block
#define RSL   16              // ring slots
#define BH    (BATCH*HID)     // 16384
#define SLOTB (BH*2)          // 32768 B per ring slot (32 x 1KB block slices)
#define RINGB (RSL*SLOTB)     // 512 KB per ring

// flag zone (ints): flagsA[64*32] | flagsB[64*32] | detect | abort
#define FZ_FB   2048
#define FZ_DET  4096
#define FZ_ABT  4160
#define FZ_TOT  4224

typedef __attribute__((ext_vector_type(8))) __bf16         bf16x8;
typedef __attribute__((ext_vector_type(8))) unsigned short u16x8;
typedef __attribute__((ext_vector_type(4))) unsigned short u16x4;
typedef __attribute__((ext_vector_type(4))) float          f32x4;

__device__ __forceinline__ unsigned short f2bf(float f) {
  unsigned int u = __builtin_bit_cast(unsigned int, f);
  u += 0x7FFFu + ((u >> 16) & 1u);
  return (unsigned short)(u >> 16);
}
__device__ __forceinline__ f32x4 pack8(f32x4 a, f32x4 b) {   // 8 f32 -> bf16x8 bits
  u16x8 r;
  r[0]=f2bf(a[0]); r[1]=f2bf(a[1]); r[2]=f2bf(a[2]); r[3]=f2bf(a[3]);
  r[4]=f2bf(b[0]); r[5]=f2bf(b[1]); r[6]=f2bf(b[2]); r[7]=f2bf(b[3]);
  return __builtin_bit_cast(f32x4, r);
}
__device__ __forceinline__ float sigm(float x)  { return 1.0f / (1.0f + __expf(-x)); }
__device__ __forceinline__ float tanh_(float x) { return 2.0f / (1.0f + __expf(-2.0f*x)) - 1.0f; }

// ---- scoped memory helpers (loads embed waitcnt unless caller drains) ----
__device__ __forceinline__ f32x4 ld16_pl(const void* p)  { f32x4 r; asm volatile("global_load_dwordx4 %0, %1, off"     : "=v"(r) : "v"(p)); return r; }
__device__ __forceinline__ f32x4 ld16_sc0(const void* p) { f32x4 r; asm volatile("global_load_dwordx4 %0, %1, off sc0" : "=v"(r) : "v"(p)); return r; }
__device__ __forceinline__ f32x4 ld16_sc1(const void* p) { f32x4 r; asm volatile("global_load_dwordx4 %0, %1, off sc1" : "=v"(r) : "v"(p)); return r; }
__device__ __forceinline__ int lddww_sc1(const void* p) {
  int r; asm volatile("global_load_dword %0, %1, off sc1\n\ts_waitcnt vmcnt(0)" : "=v"(r) : "v"(p) : "memory"); return r;
}
__device__ __forceinline__ void st16_sc0(void* p, f32x4 v) { asm volatile("global_store_dwordx4 %0, %1, off sc0" :: "v"(p), "v"(v) : "memory"); }
__device__ __forceinline__ void st16_sc1(void* p, f32x4 v) { asm volatile("global_store_dwordx4 %0, %1, off sc1" :: "v"(p), "v"(v) : "memory"); }
__device__ __forceinline__ void stdw_sc1(void* p, int v) { asm volatile("global_store_dword %0, %1, off sc1" :: "v"(p), "v"(v) : "memory"); }
__device__ __forceinline__ void vm_drain() { asm volatile("s_waitcnt vmcnt(0)" ::: "memory"); }

// ---------------- prep kernels ----------------

__global__ void prep_misc(const float* __restrict__ b_ih, const float* __restrict__ b_hh,
                          const float* __restrict__ h0,
                          int* __restrict__ flagz, float* __restrict__ bsum,
                          char* __restrict__ ring0, char* __restrict__ ring1s) {
  int i = blockIdx.x * blockDim.x + threadIdx.x;   // 32768 threads
  if (i < FZ_TOT) flagz[i] = 0;
  if (i < NL*GDIM) bsum[i] = b_ih[i] + b_hh[i];
  if (i < NL*BH) {                                  // ring slot-0, per-block 1KB slices
    int layer = i >> 14, e = i & 16383;
    int b = e >> 9, u = e & 511;
    unsigned short v = f2bf(h0[((size_t)layer*BATCH + b)*HID + u]);
    size_t off = (size_t)(u >> 4)*1024 + (size_t)b*32 + (size_t)(u & 15)*2;
    *(unsigned short*)(ring0  + (size_t)layer*RINGB + off) = v;
    *(unsigned short*)(ring1s + (size_t)layer*RINGB + off) = v;
  }
}

__global__ void prep_w(const float* __restrict__ wih, const float* __restrict__ whh,
                       unsigned short* __restrict__ wihb, unsigned short* __restrict__ whhb) {
  const int n4 = NL*GDIM*HID/4;
  for (int i = blockIdx.x*blockDim.x + threadIdx.x; i < 2*n4; i += gridDim.x*blockDim.x) {
    const float*    src = (i < n4) ? wih  : whh;
    unsigned short* dst = (i < n4) ? wihb : whhb;
    int j = (i < n4) ? i : i - n4;
    f32x4 v = *((const f32x4*)src + j);
    u16x4 o; o[0]=f2bf(v[0]); o[1]=f2bf(v[1]); o[2]=f2bf(v[2]); o[3]=f2bf(v[3]);
    *((u16x4*)dst + j) = o;
  }
}

// ---------------- persistent LSTM ----------------
// grid 256 x 512. Active: bid%8 < 2 (layer), lb = bid>>3 in [0,32). 32 blocks/layer.
// REPLAY-SAFETY (round-5): sc0 only for value-guarded ring DATA rewritten by a
// same-XCD producer this launch before its flag publishes; control state sc1-only.
// t=0 h reads (flag-unguarded) use the sc1 ring written by prep.
//
// Ring slot = 32 contiguous 1KB block slices, each [batch][unit] bf16. Producers
// gather via LDS; ONE wave stores 64x16B coalesced. Readers permute during the
// LDS staging write. Layer-1's ringPrev loads are issued only AFTER the wave-1
// poll confirms layer-0's B >= t+1 (round-9 fix).
// Polling: wave0 = own-layer flagsA (sc1); wave1 = cross-layer flagsB (sc1).
// Publish: wave0 stores primary ring (fast sc0/slow sc1), drains, flagA=t+1
// (slow layer-0 also flagB=t+1). Layer-0-fast wave1 mirrors to sc1 ring,
// drains, flagB=t+1. Layer-1 wave1 publishes flagB=t+1 after B1 (progress-
// only). Waves 2/3 (layer-1) store out rows coalesced. Terminal publish after
// the loop. No thread ever breaks out of the t-loop (aborts only disable
// polling) — hang-proof barrier structure.

__global__ __launch_bounds__(512, 2) void lstm_persist(
    const float* __restrict__ x, const float* __restrict__ c0,
    const unsigned short* __restrict__ wihb, const unsigned short* __restrict__ whhb,
    const float* __restrict__ bsum,
    char* __restrict__ ring0, char* __restrict__ ring1s,
    int* __restrict__ flagz, float* __restrict__ out) {

  const int bid = blockIdx.x;
  const int r8  = bid & 7;
  if (r8 >= NL) return;
  const int layer = r8;
  const int lb    = bid >> 3;                 // 0..31
  const int actIdx = layer*NBL + lb;          // 0..63
  const int tid  = threadIdx.x;
  const int lane = tid & 63;
  const int wave = tid >> 6;                  // 0..7
  const int mh = wave & 1, nh = wave >> 1;    // batch-half, row-group (0..3)
  const int col = lane & 15, kg = lane >> 4;
  const int gt  = col & 3;                    // gate index (i,f,g,o)
  const int uu  = nh*4 + (col >> 2);          // unit-local 0..15
  const int u0  = lb * UPB;
  const int gu  = u0 + uu;                    // global hidden unit
  const int grow = gt*HID + gu;               // gate-matrix row
  const int tb  = mh*16 + kg*4 + gt;          // this thread's batch (post-transpose)

  int* flagsA = flagz;
  int* flagsB = flagz + FZ_FB;
  int* detect = flagz + FZ_DET;
  int* abortp = flagz + FZ_ABT;

  __shared__ __align__(16) f32x4 smem[4096];           // h frags [0,2048), x frags [2048,4096)
  __shared__ __align__(16) unsigned short hbuf16[512]; // h slice [batch][unit] bf16, 1KB
  __shared__ __align__(16) float houtf[512];           // h slice f32 (layer-1 out), 2KB

  // ---- weight fragments (register-file resident; in-loop touches pin) ----
  f32x4 wfx[16], wfh[16];
  {
    const unsigned short* wxr = wihb + ((size_t)(layer*GDIM + grow))*HID + kg*8;
    const unsigned short* whr = whhb + ((size_t)(layer*GDIM + grow))*HID + kg*8;
#pragma unroll
    for (int ks = 0; ks < 16; ++ks) {
      wfx[ks] = *(const f32x4*)(wxr + ks*32);
      wfh[ks] = *(const f32x4*)(whr + ks*32);
    }
  }

  // ---- per-thread cell state ----
  float c = c0[((size_t)layer*BATCH + tb)*HID + gu];
  const float bi  = bsum[layer*GDIM + 0*HID + gu];
  const float bfv = bsum[layer*GDIM + 1*HID + gu];
  const float bg  = bsum[layer*GDIM + 2*HID + gu];
  const float bo  = bsum[layer*GDIM + 3*HID + gu];

  char* ringF = ring0  + (size_t)layer*RINGB;   // sc0 own-layer ring (fast data)
  char* ringS = ring1s + (size_t)layer*RINGB;   // sc1 own-layer ring
  const char* ringPrev = ring1s;                 // layer-0's sc1 ring (x for layer 1)
  int* myfA = flagsA + actIdx*32;
  int* myfB = flagsB + actIdx*32;
  const bool pl = lane < NBL;
  const int* fpOwnA = flagsA + (layer*NBL + lane)*32;
  const int* fpOthB = flagsB + ((1-layer)*NBL + lane)*32;
  int seenOwn = 0, seenOth = 0;
  bool dead = false;

  // ---- placement detection (sc1-only) ----
  int xcc = 0;
  asm volatile("s_getreg_b32 %0, hwreg(HW_REG_XCC_ID)" : "=s"(xcc));
  if (tid == 0) stdw_sc1(detect + actIdx, xcc + 1);
  int dv = 0;
  {
    int spins = 0;
    for (;;) {
      if (dv == 0) dv = lddww_sc1(detect + lane);
      if (__all(dv != 0)) break;
      if (((++spins) & 255) == 0) {
        if (lddww_sc1(abortp)) { dead = true; break; }
        if (spins >= (1 << 20)) { stdw_sc1(abortp, 1); dead = true; break; }
      }
    }
  }
  const int dref0 = __shfl(dv, 0, 64), dref1 = __shfl(dv, 32, 64);
  const bool fastL0 = __all((lane < 32) ? (dv != 0 && dv == dref0) : 1);
  const bool fastL1 = __all((lane >= 32) ? (dv != 0 && dv == dref1) : 1);
  const bool fast = (layer ? fastL1 : fastL0) && !dead;

  // reader address pieces (fragment id -> slice byte offset within a slot)
  int roff[4];
#pragma unroll
  for (int q = 0; q < 4; ++q) {
    int id = q*512 + tid;
    int mh2 = id >> 10, ks2 = (id >> 6) & 15, lf = id & 63;
    int ug = ks2*32 + (lf >> 4)*8;
    int batch = mh2*16 + (lf & 15);
    roff[q] = (ug >> 4)*1024 + batch*32 + (ug & 8)*2;
  }

  for (int t = 0; t < T_LEN; ++t) {
    const int slotR = t & (RSL-1);
    const int slotW = (t+1) & (RSL-1);

    // ---- 0. pin weights (loop-carried opaque touch) ----
#pragma unroll
    for (int ks = 0; ks < 16; ++ks)
      asm volatile("" : "+v"(wfx[ks]), "+v"(wfh[ks]));

    // ---- 1. layer-0 x prefetch ONLY (immutable global x, no flag dependency) ----
    f32x4 xpre[8];
    if (layer == 0) {
#pragma unroll
      for (int q = 0; q < 4; ++q) {
        int id = q*512 + tid;
        int mh2 = id >> 10, ks2 = (id >> 6) & 15, lf = id & 63;
        const float* s = x + ((size_t)t*BATCH + mh2*16 + (lf & 15))*HID + ks2*32 + (lf >> 4)*8;
        xpre[2*q]   = ld16_pl(s);
        xpre[2*q+1] = ld16_pl(s + 4);
      }
    }

    // ---- 2. polls: wave0 = own-layer flagsA; wave1 = cross-layer flagsB ----
    if (wave == 0 && !dead) {
      int spins = 0;
      while (!__all(pl ? (seenOwn >= t) : 1)) {
        if (pl && seenOwn < t) { int v = lddww_sc1(fpOwnA); if (v > seenOwn) seenOwn = v; }
        if (((++spins) & 255) == 0) {
          if (lddww_sc1(abortp)) { dead = true; break; }
          if (spins >= (1 << 21)) { stdw_sc1(abortp, 1); dead = true; break; }
        }
      }
    }
    if (wave == 1 && !dead) {
      const int tgt = (layer == 0) ? (t - 14) : (t + 1);
      int spins = 0;
      while (!__all(pl ? (seenOth >= tgt) : 1)) {
        if (pl && seenOth < tgt) { int v = lddww_sc1(fpOthB); if (v > seenOth) seenOth = v; }
        if (((++spins) & 255) == 0) {
          if (lddww_sc1(abortp)) { dead = true; break; }
          if (spins >= (1 << 21)) { stdw_sc1(abortp, 1); dead = true; break; }
        }
      }
    }
    __syncthreads();   // B0: all deps confirmed for the whole block

    // ---- 3. dependent loads (AFTER B0): xq then hq ----
    f32x4 xq[4], hq[4];
    if (layer == 1) {
      const char* p = ringPrev + (size_t)slotW*SLOTB;
#pragma unroll
      for (int q = 0; q < 4; ++q) xq[q] = ld16_sc1(p + roff[q]);
    }
    if (fast && t > 0) {
      const char* p = ringF + (size_t)slotR*SLOTB;
#pragma unroll
      for (int q = 0; q < 4; ++q) hq[q] = ld16_sc0(p + roff[q]);
    } else {
      const char* p = ringS + (size_t)slotR*SLOTB;
#pragma unroll
      for (int q = 0; q < 4; ++q) hq[q] = ld16_sc1(p + roff[q]);
    }
    vm_drain();   // all asm loads (xpre/xq/hq) now valid

    // ---- 4. stage to LDS (fragment permutation happens here) ----
#pragma unroll
    for (int q = 0; q < 4; ++q) smem[q*512 + tid] = hq[q];
    if (layer == 0) {
#pragma unroll
      for (int q = 0; q < 4; ++q) smem[2048 + q*512 + tid] = pack8(xpre[2*q], xpre[2*q+1]);
    } else {
#pragma unroll
      for (int q = 0; q < 4; ++q) smem[2048 + q*512 + tid] = xq[q];
    }
    __syncthreads();   // B1

    // layer-1 progress flag (ringPrev reads for step t complete) — early
    if (layer == 1 && wave == 1 && lane == 0) stdw_sc1(myfB, t + 1);

    // ---- 5. fragment reads + two independent MFMA chains ----
    f32x4 accx = {0.f,0.f,0.f,0.f}, acch = {0.f,0.f,0.f,0.f};
    {
      const f32x4* hb = (const f32x4*)smem;
      const f32x4* xb = (const f32x4*)smem + 2048;
#pragma unroll
      for (int ks = 0; ks < 16; ++ks) {
        f32x4 ah = hb[(mh*16 + ks)*64 + lane];
        f32x4 av = xb[(mh*16 + ks)*64 + lane];
        accx = __builtin_amdgcn_mfma_f32_16x16x32_bf16(
                 __builtin_bit_cast(bf16x8, av), __builtin_bit_cast(bf16x8, wfx[ks]), accx, 0,0,0);
        acch = __builtin_amdgcn_mfma_f32_16x16x32_bf16(
                 __builtin_bit_cast(bf16x8, ah), __builtin_bit_cast(bf16x8, wfh[ks]), acch, 0,0,0);
      }
    }
    const f32x4 acc = accx + acch;

    // ---- 6. in-wave 4x4 butterfly transpose -> (1 batch x 4 gates) ----
    float m0 = acc[0], m1 = acc[1], m2 = acc[2], m3 = acc[3];
    {
      float s0 = __shfl_xor(m0, 1), s1 = __shfl_xor(m1, 1),
            s2 = __shfl_xor(m2, 1), s3 = __shfl_xor(m3, 1);
      if (gt & 1) { m0 = s1; m2 = s3; } else { m1 = s0; m3 = s2; }
      s0 = __shfl_xor(m0, 2); s1 = __shfl_xor(m1, 2);
      s2 = __shfl_xor(m2, 2); s3 = __shfl_xor(m3, 2);
      if (gt & 2) { m0 = s2; m1 = s3; } else { m2 = s0; m3 = s1; }
    }
    const float iv = sigm(m0 + bi), fv = sigm(m1 + bfv);
    const float gv = tanh_(m2 + bg), ov = sigm(m3 + bo);
    c = fv*c + iv*gv;
    const float h = ov * tanh_(c);

    // ---- 7. gather h into LDS, then coalesced publish ----
    hbuf16[tb*16 + uu] = f2bf(h);
    if (layer == 1) houtf[tb*16 + uu] = h;
    if (t == T_LEN-1) {
      out[(size_t)T_LEN*BH + ((size_t)layer*BATCH + tb)*HID + gu] = h;
      out[(size_t)T_LEN*BH + (size_t)NL*BH + ((size_t)layer*BATCH + tb)*HID + gu] = c;
    }
    __syncthreads();   // B4: hbuf16/houtf complete

    if (wave == 0) {
      f32x4 v = *(const f32x4*)((const char*)hbuf16 + lane*16);
      char* d = (fast ? ringF : ringS) + (size_t)slotW*SLOTB + lb*1024 + lane*16;
      if (fast) st16_sc0(d, v); else st16_sc1(d, v);
      vm_drain();
      if (lane == 0) {
        stdw_sc1(myfA, t + 1);
        if (layer == 0 && !fast) stdw_sc1(myfB, t + 1);
      }
    } else if (wave == 1 && layer == 0 && fast) {
      f32x4 v = *(const f32x4*)((const char*)hbuf16 + lane*16);
      st16_sc1(ringS + (size_t)slotW*SLOTB + lb*1024 + lane*16, v);
      vm_drain();
      if (lane == 0) stdw_sc1(myfB, t + 1);
    } else if (layer == 1 && (wave == 2 || wave == 3)) {
      int l2 = (wave - 2)*64 + lane;          // 0..127 -> 16B chunks of 2KB
      int b2 = l2 >> 2, part = l2 & 3;
      f32x4 v = *(const f32x4*)((const char*)houtf + b2*64 + part*16);
      *(f32x4*)(out + (size_t)t*BH + (size_t)b2*HID + u0 + part*4) = v;
    }
  }

  // ---- terminal publish: drain everything, advertise completion ----
  vm_drain();
  __syncthreads();
  if (tid == 0) { stdw_sc1(myfA, T_LEN + 1); stdw_sc1(myfB, T_LEN + 1); }
}

// ---------------- host launch ----------------

extern "C" void kernel_launch(void* const* d_in, const int* in_sizes, int n_in,
                              void* d_out, int out_size, void* d_ws, size_t ws_size,
                              hipStream_t stream) {
  const float* x    = (const float*)d_in[0];
  const float* w_ih = (const float*)d_in[1];
  const float* w_hh = (const float*)d_in[2];
  const float* b_ih = (const float*)d_in[3];
  const float* b_hh = (const float*)d_in[4];
  const float* h0   = (const float*)d_in[5];
  const float* c0   = (const float*)d_in[6];
  float* out = (float*)d_out;

  char* ws = (char*)d_ws;
  size_t off = 0;
  auto alloc = [&](size_t bytes) -> void* {
    off = (off + 255) & ~(size_t)255;
    void* p = ws + off;
    off += bytes;
    return p;
  };
  int*            flagz = (int*)alloc((size_t)FZ_TOT * sizeof(int));
  float*          bsum  = (float*)alloc((size_t)NL*GDIM*sizeof(float));
  char*           ring0 = (char*)alloc((size_t)NL*RINGB);
  char*           ring1s= (char*)alloc((size_t)NL*RINGB);
  unsigned short* wihb  = (unsigned short*)alloc((size_t)NL*GDIM*HID*2);
  unsigned short* whhb  = (unsigned short*)alloc((size_t)NL*GDIM*HID*2);
  (void)ws_size;

  prep_misc<<<128, 256, 0, stream>>>(b_ih, b_hh, h0, flagz, bsum, ring0, ring1s);
  prep_w<<<1024, 256, 0, stream>>>(w_ih, w_hh, wihb, whhb);
  lstm_persist<<<256, 512, 0, stream>>>(x, c0, wihb, whhb, bsum,
                                        ring0, ring1s, flagz, out);
  (void)in_sizes; (void)n_in; (void)out_size;
}